// Round 3
// baseline (322.809 us; speedup 1.0000x reference)
//
#include <hip/hip_runtime.h>

#define NCH 64      // channels
#define KOFF 27     // kernel offsets
#define EPSV 1e-5f

typedef __attribute__((ext_vector_type(8))) short  bf16x8;
typedef __attribute__((ext_vector_type(4))) float  f32x4;
typedef __attribute__((ext_vector_type(8))) unsigned short u16x8;

__device__ __forceinline__ unsigned short f2bf(float x) {
    unsigned int u = __float_as_uint(x);
    u += 0x7fffu + ((u >> 16) & 1u);       // round-to-nearest-even
    return (unsigned short)(u >> 16);
}

// ---------------------------------------------------------------------------
// Fused prep: zero stats | W1->Wt1 | W2->Wt2 (B-fragment order) | feats->bf16
// Wt[(((k*2+s)*4+ct)*64+lane)*8 + j] = W[k][s*32+(lane>>4)*8+j][ct*16+(lane&15)]
// ---------------------------------------------------------------------------
__global__ __launch_bounds__(256)
void prep_kernel(const float* __restrict__ feats,
                 const float* __restrict__ W1, const float* __restrict__ W2,
                 unsigned short* __restrict__ fbf,
                 unsigned short* __restrict__ wt1, unsigned short* __restrict__ wt2,
                 float* __restrict__ stat, int total8)
{
    const int b = blockIdx.x;
    if (b == 0) {
        stat[threadIdx.x] = 0.f;           // 256 floats: stats1+stats2
        return;
    }
    if (b <= 108) {
        const float* W = (b <= 54) ? W1 : W2;
        unsigned short* Wt = (b <= 54) ? wt1 : wt2;
        const int t = (b <= 54 ? b - 1 : b - 55) * 256 + threadIdx.x; // 0..13823
        const int l  = t & 63;
        const int ct = (t >> 6) & 3;
        const int s  = (t >> 8) & 1;
        const int k  = t >> 9;
        const int d     = ct * 16 + (l & 15);
        const int cbase = s * 32 + (l >> 4) * 8;
        u16x8 o;
#pragma unroll
        for (int j = 0; j < 8; ++j)
            o[j] = f2bf(W[(size_t)k * 4096 + (size_t)(cbase + j) * 64 + d]);
        reinterpret_cast<u16x8*>(Wt)[t] = o;
        return;
    }
    const int idx = (b - 109) * 256 + threadIdx.x;
    if (idx >= total8) return;
    const float4* xp = reinterpret_cast<const float4*>(feats) + (size_t)idx * 2;
    const float4 a = xp[0], c = xp[1];
    u16x8 o;
    o[0] = f2bf(a.x); o[1] = f2bf(a.y); o[2] = f2bf(a.z); o[3] = f2bf(a.w);
    o[4] = f2bf(c.x); o[5] = f2bf(c.y); o[6] = f2bf(c.z); o[7] = f2bf(c.w);
    reinterpret_cast<u16x8*>(fbf)[idx] = o;
}

// ---------------------------------------------------------------------------
// Barrier-free gathered conv via MFMA 16x16x32 bf16 + fused channel stats.
// One wave per block: 64 voxels x 64 out-channels, acc[4][4] f32x4.
// A-fragments and B-fragments loaded DIRECTLY from global (no LDS staging,
// no __syncthreads) with a register double-buffer so the compiler can emit
// partial vmcnt waits and keep prefetches in flight.
// ---------------------------------------------------------------------------
__global__ __launch_bounds__(64, 2)
void conv_mfma_kernel(const unsigned short* __restrict__ fin,
                      const int* __restrict__ nbr,
                      const unsigned short* __restrict__ Wt,
                      const float* __restrict__ bias,
                      float* __restrict__ out, float* __restrict__ stat, int N)
{
    __shared__ int s_idx[KOFF * 64 + 64];   // +pad, wave-private (one wave/block)

    const int lane = threadIdx.x;           // 0..63
    const int n0   = blockIdx.x * 64;
    const int m    = lane & 15;
    const int quad = lane >> 4;

    // stage this wave's 64 voxels' indices (contiguous region of nbr)
    {
        const int rem  = N - n0;
        const int maxi = (rem < 64 ? rem : 64) * KOFF;
        const int* nb  = nbr + (size_t)n0 * KOFF;
#pragma unroll
        for (int j = 0; j < KOFF; ++j) {
            const int p = j * 64 + lane;
            s_idx[p] = (p < maxi) ? nb[p] : 0;
        }
        // single wave: LDS RAW within the wave needs no barrier
    }

    f32x4 acc[4][4];
#pragma unroll
    for (int mt = 0; mt < 4; ++mt)
#pragma unroll
        for (int ct = 0; ct < 4; ++ct) acc[mt][ct] = (f32x4){0.f, 0.f, 0.f, 0.f};

    bf16x8 A[2][4][2];   // [buf][m-tile][s]
    bf16x8 B[2][2][4];   // [buf][s][ct]

#define LOADK(k, p)                                                          \
    {                                                                        \
        _Pragma("unroll")                                                    \
        for (int mt = 0; mt < 4; ++mt) {                                     \
            const int r = s_idx[(mt * 16 + m) * KOFF + (k)];                 \
            const unsigned short* fp = fin + (size_t)r * NCH + quad * 8;     \
            A[p][mt][0] = *reinterpret_cast<const bf16x8*>(fp);              \
            A[p][mt][1] = *reinterpret_cast<const bf16x8*>(fp + 32);         \
        }                                                                    \
        const unsigned short* wp = Wt + (size_t)(k) * 4096 + lane * 8;       \
        _Pragma("unroll")                                                    \
        for (int s = 0; s < 2; ++s)                                          \
            _Pragma("unroll")                                                \
            for (int ct = 0; ct < 4; ++ct)                                   \
                B[p][s][ct] =                                                \
                    *reinterpret_cast<const bf16x8*>(wp + (s * 4 + ct) * 512);\
    }

#define DOMFMA(p)                                                            \
    {                                                                        \
        _Pragma("unroll")                                                    \
        for (int mt = 0; mt < 4; ++mt)                                       \
            _Pragma("unroll")                                                \
            for (int s = 0; s < 2; ++s)                                      \
                _Pragma("unroll")                                            \
                for (int ct = 0; ct < 4; ++ct)                               \
                    acc[mt][ct] = __builtin_amdgcn_mfma_f32_16x16x32_bf16(   \
                        A[p][mt][s], B[p][s][ct], acc[mt][ct], 0, 0, 0);     \
    }

    LOADK(0, 0);
#pragma unroll 1
    for (int k = 0; k < KOFF - 1; k += 2) {
        LOADK(k + 1, 1);
        DOMFMA(0);
        LOADK(k + 2, 0);
        DOMFMA(1);
    }
    DOMFMA(0);   // k = 26

    // epilogue: D layout col=lane&15, row=quad*4+reg; fused per-channel stats
#pragma unroll
    for (int ct = 0; ct < 4; ++ct) {
        const int ch = ct * 16 + m;
        const float bv = bias[ch];
        float s = 0.f, q = 0.f;
#pragma unroll
        for (int mt = 0; mt < 4; ++mt) {
#pragma unroll
            for (int r = 0; r < 4; ++r) {
                const int vox = n0 + mt * 16 + quad * 4 + r;
                if (vox < N) {
                    const float v = acc[mt][ct][r] + bv;
                    out[(size_t)vox * NCH + ch] = v;
                    s += v;
                    q += v * v;
                }
            }
        }
        s += __shfl_xor(s, 16, 64);
        s += __shfl_xor(s, 32, 64);
        q += __shfl_xor(q, 16, 64);
        q += __shfl_xor(q, 32, 64);
        if (quad == 0) {
            atomicAdd(&stat[ch], s);
            atomicAdd(&stat[64 + ch], q);
        }
    }
#undef LOADK
#undef DOMFMA
}

// ---------------------------------------------------------------------------
// BN + ReLU, fp32 in -> bf16 out (conv2's gather input). 8 elems/thread.
// ---------------------------------------------------------------------------
__global__ __launch_bounds__(256)
void bn_relu_bf16_kernel(const float* __restrict__ x, const float* __restrict__ sums,
                         const float* __restrict__ gmm, const float* __restrict__ bet,
                         float invN, unsigned short* __restrict__ y, int total8)
{
    const int idx = blockIdx.x * 256 + threadIdx.x;
    if (idx >= total8) return;
    const int c0 = (idx & 7) * 8;
    const float4* xp = reinterpret_cast<const float4*>(x) + (size_t)idx * 2;
    const float4 a = xp[0], b = xp[1];
    float v[8] = {a.x, a.y, a.z, a.w, b.x, b.y, b.z, b.w};
    u16x8 o;
#pragma unroll
    for (int i = 0; i < 8; ++i) {
        const int c = c0 + i;
        const float mu  = sums[c] * invN;
        const float var = sums[64 + c] * invN - mu * mu;
        const float rs  = rsqrtf(var + EPSV);
        const float sc  = gmm[c] * rs;
        const float sh  = bet[c] - mu * sc;
        o[i] = f2bf(fmaxf(fmaf(v[i], sc, sh), 0.f));
    }
    reinterpret_cast<u16x8*>(y)[idx] = o;
}

// ---------------------------------------------------------------------------
// BN + residual + ReLU, in-place fp32 (final output)
// ---------------------------------------------------------------------------
__global__ __launch_bounds__(256)
void bn_res_relu_kernel(float* __restrict__ x, const float* __restrict__ feats,
                        const float* __restrict__ sums, const float* __restrict__ gmm,
                        const float* __restrict__ bet, float invN, int total4)
{
    const int idx = blockIdx.x * blockDim.x + threadIdx.x;
    if (idx >= total4) return;
    float4 v = reinterpret_cast<float4*>(x)[idx];
    const float4 f = reinterpret_cast<const float4*>(feats)[idx];
    const int c0 = (idx & 15) * 4;
    float sc[4], sh[4];
#pragma unroll
    for (int i = 0; i < 4; ++i) {
        const int c = c0 + i;
        const float mu  = sums[c] * invN;
        const float var = sums[64 + c] * invN - mu * mu;
        const float rs  = rsqrtf(var + EPSV);
        sc[i] = gmm[c] * rs;
        sh[i] = bet[c] - mu * sc[i];
    }
    v.x = fmaxf(fmaf(v.x, sc[0], sh[0]) + f.x, 0.f);
    v.y = fmaxf(fmaf(v.y, sc[1], sh[1]) + f.y, 0.f);
    v.z = fmaxf(fmaf(v.z, sc[2], sh[2]) + f.z, 0.f);
    v.w = fmaxf(fmaf(v.w, sc[3], sh[3]) + f.w, 0.f);
    reinterpret_cast<float4*>(x)[idx] = v;
}

extern "C" void kernel_launch(void* const* d_in, const int* in_sizes, int n_in,
                              void* d_out, int out_size, void* d_ws, size_t ws_size,
                              hipStream_t stream)
{
    const float* feats = (const float*)d_in[0];
    const int*   nbr   = (const int*)d_in[1];
    const float* W1    = (const float*)d_in[2];
    const float* b1    = (const float*)d_in[3];
    const float* g1    = (const float*)d_in[4];
    const float* be1   = (const float*)d_in[5];
    const float* W2    = (const float*)d_in[6];
    const float* b2    = (const float*)d_in[7];
    const float* g2    = (const float*)d_in[8];
    const float* be2   = (const float*)d_in[9];
    float* out = (float*)d_out;

    const int N  = in_sizes[0] / NCH;          // 100000
    const int NC = N * NCH;                    // 6,400,000
    const float invN = 1.0f / (float)N;

    // workspace layout
    float*          h0   = (float*)d_ws;                       // [N*C] fp32
    unsigned short* fbf  = (unsigned short*)(h0 + NC);         // [N*C] bf16
    unsigned short* hbf  = fbf + NC;                           // [N*C] bf16
    unsigned short* wt1  = hbf + NC;                           // 110592 bf16
    unsigned short* wt2  = wt1 + KOFF * 4096;                  // 110592 bf16
    float*          stat = (float*)(wt2 + KOFF * 4096);        // 256 fp32

    const int total8   = NC / 8;                               // 800000
    const int castGrid = (total8 + 255) / 256;                 // 3125
    const int prepGrid = 1 + 108 + castGrid;                   // 3234
    const int convGrid = (N + 63) / 64;                        // 1563

    prep_kernel<<<prepGrid, 256, 0, stream>>>(feats, W1, W2, fbf, wt1, wt2,
                                              stat, total8);
    conv_mfma_kernel<<<convGrid, 64, 0, stream>>>(fbf, nbr, wt1, b1, h0, stat, N);
    bn_relu_bf16_kernel<<<castGrid, 256, 0, stream>>>(h0, stat, g1, be1, invN,
                                                      hbf, total8);
    conv_mfma_kernel<<<convGrid, 64, 0, stream>>>(hbf, nbr, wt2, b2, out,
                                                  stat + 128, N);
    bn_res_relu_kernel<<<(NC / 4 + 255) / 256, 256, 0, stream>>>(
        out, feats, stat + 128, g2, be2, invN, NC / 4);
}

// Round 4
// 321.312 us; speedup vs baseline: 1.0047x; 1.0047x over previous
//
#include <hip/hip_runtime.h>

#define NCH 64      // channels
#define KOFF 27     // kernel offsets
#define EPSV 1e-5f

typedef __attribute__((ext_vector_type(8))) short  bf16x8;
typedef __attribute__((ext_vector_type(4))) float  f32x4;
typedef __attribute__((ext_vector_type(8))) unsigned short u16x8;

__device__ __forceinline__ unsigned short f2bf(float x) {
    unsigned int u = __float_as_uint(x);
    u += 0x7fffu + ((u >> 16) & 1u);       // round-to-nearest-even
    return (unsigned short)(u >> 16);
}

// ---------------------------------------------------------------------------
// Fused prep: zero stats | W1->Wt1 | W2->Wt2 (B-fragment order) | feats->bf16
// Wt[(((k*2+s)*4+ct)*64+lane)*8 + j] = W[k][s*32+(lane>>4)*8+j][ct*16+(lane&15)]
// ---------------------------------------------------------------------------
__global__ __launch_bounds__(256)
void prep_kernel(const float* __restrict__ feats,
                 const float* __restrict__ W1, const float* __restrict__ W2,
                 unsigned short* __restrict__ fbf,
                 unsigned short* __restrict__ wt1, unsigned short* __restrict__ wt2,
                 float* __restrict__ stat, int total8)
{
    const int b = blockIdx.x;
    if (b == 0) {
        stat[threadIdx.x] = 0.f;           // 256 floats: stats1+stats2
        return;
    }
    if (b <= 108) {
        const float* W = (b <= 54) ? W1 : W2;
        unsigned short* Wt = (b <= 54) ? wt1 : wt2;
        const int t = (b <= 54 ? b - 1 : b - 55) * 256 + threadIdx.x; // 0..13823
        const int l  = t & 63;
        const int ct = (t >> 6) & 3;
        const int s  = (t >> 8) & 1;
        const int k  = t >> 9;
        const int d     = ct * 16 + (l & 15);
        const int cbase = s * 32 + (l >> 4) * 8;
        u16x8 o;
#pragma unroll
        for (int j = 0; j < 8; ++j)
            o[j] = f2bf(W[(size_t)k * 4096 + (size_t)(cbase + j) * 64 + d]);
        reinterpret_cast<u16x8*>(Wt)[t] = o;
        return;
    }
    const int idx = (b - 109) * 256 + threadIdx.x;
    if (idx >= total8) return;
    const float4* xp = reinterpret_cast<const float4*>(feats) + (size_t)idx * 2;
    const float4 a = xp[0], c = xp[1];
    u16x8 o;
    o[0] = f2bf(a.x); o[1] = f2bf(a.y); o[2] = f2bf(a.z); o[3] = f2bf(a.w);
    o[4] = f2bf(c.x); o[5] = f2bf(c.y); o[6] = f2bf(c.z); o[7] = f2bf(c.w);
    reinterpret_cast<u16x8*>(fbf)[idx] = o;
}

// ---------------------------------------------------------------------------
// Split-K gathered conv via MFMA 16x16x32 bf16 + fused channel stats.
// Block = 4 waves sharing 64 voxels x 64 out-channels. Wave w handles
// k = (3-w) + 4j (6 or 7 offsets), NO barrier in the K-loop (register
// double-buffer, direct-from-global A and B fragments). Partial sums are
// tree-reduced through LDS (3 barriers, all after the gathers complete).
// ---------------------------------------------------------------------------
__global__ __launch_bounds__(256, 2)
void conv_mfma_kernel(const unsigned short* __restrict__ fin,
                      const int* __restrict__ nbr,
                      const unsigned short* __restrict__ Wt,
                      const float* __restrict__ bias,
                      float* __restrict__ out, float* __restrict__ stat, int N)
{
    __shared__ int   s_idx[KOFF * 64];        // byte offsets into fin
    __shared__ float red[2][64 * 68];         // stride 68: <=2-way LDS alias

    const int t    = threadIdx.x;
    const int lane = t & 63;
    const int w    = t >> 6;
    const int n0   = blockIdx.x * 64;
    const int m    = lane & 15;
    const int quad = lane >> 4;

    {   // cooperative index stage (pre-scaled to byte offsets)
        const int rem  = N - n0;
        const int maxi = (rem < 64 ? rem : 64) * KOFF;
        const int* nb  = nbr + (size_t)n0 * KOFF;
        for (int p = t; p < KOFF * 64; p += 256)
            s_idx[p] = ((p < maxi) ? nb[p] : 0) * (NCH * 2);
    }
    __syncthreads();

    f32x4 acc[4][4];
#pragma unroll
    for (int mt = 0; mt < 4; ++mt)
#pragma unroll
        for (int ct = 0; ct < 4; ++ct) acc[mt][ct] = (f32x4){0.f, 0.f, 0.f, 0.f};

    bf16x8 A[2][4][2];   // [buf][m-tile][s]
    bf16x8 B[2][2][4];   // [buf][s][ct]
    const char* finB = (const char*)fin;

#define LOADK(kk, p)                                                         \
    {                                                                        \
        _Pragma("unroll")                                                    \
        for (int mt = 0; mt < 4; ++mt) {                                     \
            const int ofs = s_idx[(mt * 16 + m) * KOFF + (kk)];              \
            const char* fp = finB + ofs + quad * 16;                         \
            A[p][mt][0] = *reinterpret_cast<const bf16x8*>(fp);              \
            A[p][mt][1] = *reinterpret_cast<const bf16x8*>(fp + 64);         \
        }                                                                    \
        const unsigned short* wp = Wt + (size_t)(kk) * 4096 + lane * 8;      \
        _Pragma("unroll")                                                    \
        for (int s = 0; s < 2; ++s)                                          \
            _Pragma("unroll")                                                \
            for (int ct = 0; ct < 4; ++ct)                                   \
                B[p][s][ct] =                                                \
                    *reinterpret_cast<const bf16x8*>(wp + (s * 4 + ct) * 512);\
    }

#define DOMFMA(p)                                                            \
    {                                                                        \
        _Pragma("unroll")                                                    \
        for (int mt = 0; mt < 4; ++mt)                                       \
            _Pragma("unroll")                                                \
            for (int s = 0; s < 2; ++s)                                      \
                _Pragma("unroll")                                            \
                for (int ct = 0; ct < 4; ++ct)                               \
                    acc[mt][ct] = __builtin_amdgcn_mfma_f32_16x16x32_bf16(   \
                        A[p][mt][s], B[p][s][ct], acc[mt][ct], 0, 0, 0);     \
    }

    // wave w handles k = (3-w) + 4j ; wave 0 gets 6 (it also runs the epilogue)
    const int kstart = 3 - w;
    const int nk     = (w == 0) ? 6 : 7;

    LOADK(kstart, 0);
    int j = 0;
#pragma unroll 1
    for (; j + 2 < nk; j += 2) {
        LOADK(kstart + 4 * (j + 1), 1);
        DOMFMA(0);
        LOADK(kstart + 4 * (j + 2), 0);
        DOMFMA(1);
    }
    if (nk - j == 2) {
        LOADK(kstart + 4 * (j + 1), 1);
        DOMFMA(0);
        DOMFMA(1);
    } else {
        DOMFMA(0);
    }

#define WRITE_ACC(buf)                                                       \
    {                                                                        \
        _Pragma("unroll")                                                    \
        for (int mt = 0; mt < 4; ++mt)                                       \
            _Pragma("unroll")                                                \
            for (int ct = 0; ct < 4; ++ct)                                   \
                *reinterpret_cast<f32x4*>(                                   \
                    &buf[(ct * 16 + m) * 68 + mt * 16 + quad * 4]) =         \
                    acc[mt][ct];                                             \
    }
#define READ_ADD(buf)                                                        \
    {                                                                        \
        _Pragma("unroll")                                                    \
        for (int mt = 0; mt < 4; ++mt)                                       \
            _Pragma("unroll")                                                \
            for (int ct = 0; ct < 4; ++ct)                                   \
                acc[mt][ct] += *reinterpret_cast<const f32x4*>(              \
                    &buf[(ct * 16 + m) * 68 + mt * 16 + quad * 4]);          \
    }

    // tree reduction: (1)+(3) -> (0)+(2) -> (0)
    if (w == 1) WRITE_ACC(red[0])
    else if (w == 3) WRITE_ACC(red[1])
    __syncthreads();
    if (w == 0) READ_ADD(red[0])
    else if (w == 2) { READ_ADD(red[1]) WRITE_ACC(red[1]) }
    __syncthreads();

    if (w == 0) {
        READ_ADD(red[1])
        // epilogue: D layout col=lane&15, row=quad*4+reg; fused stats
#pragma unroll
        for (int ct = 0; ct < 4; ++ct) {
            const int ch = ct * 16 + m;
            const float bv = bias[ch];
            float s = 0.f, q = 0.f;
#pragma unroll
            for (int mt = 0; mt < 4; ++mt) {
#pragma unroll
                for (int r = 0; r < 4; ++r) {
                    const int vox = n0 + mt * 16 + quad * 4 + r;
                    if (vox < N) {
                        const float v = acc[mt][ct][r] + bv;
                        out[(size_t)vox * NCH + ch] = v;
                        s += v;
                        q += v * v;
                    }
                }
            }
            s += __shfl_xor(s, 16, 64);
            s += __shfl_xor(s, 32, 64);
            q += __shfl_xor(q, 16, 64);
            q += __shfl_xor(q, 32, 64);
            if (quad == 0) {
                atomicAdd(&stat[ch], s);
                atomicAdd(&stat[64 + ch], q);
            }
        }
    }
#undef LOADK
#undef DOMFMA
#undef WRITE_ACC
#undef READ_ADD
}

// ---------------------------------------------------------------------------
// BN + ReLU, fp32 in -> bf16 out (conv2's gather input). 8 elems/thread.
// ---------------------------------------------------------------------------
__global__ __launch_bounds__(256)
void bn_relu_bf16_kernel(const float* __restrict__ x, const float* __restrict__ sums,
                         const float* __restrict__ gmm, const float* __restrict__ bet,
                         float invN, unsigned short* __restrict__ y, int total8)
{
    const int idx = blockIdx.x * 256 + threadIdx.x;
    if (idx >= total8) return;
    const int c0 = (idx & 7) * 8;
    const float4* xp = reinterpret_cast<const float4*>(x) + (size_t)idx * 2;
    const float4 a = xp[0], b = xp[1];
    float v[8] = {a.x, a.y, a.z, a.w, b.x, b.y, b.z, b.w};
    u16x8 o;
#pragma unroll
    for (int i = 0; i < 8; ++i) {
        const int c = c0 + i;
        const float mu  = sums[c] * invN;
        const float var = sums[64 + c] * invN - mu * mu;
        const float rs  = rsqrtf(var + EPSV);
        const float sc  = gmm[c] * rs;
        const float sh  = bet[c] - mu * sc;
        o[i] = f2bf(fmaxf(fmaf(v[i], sc, sh), 0.f));
    }
    reinterpret_cast<u16x8*>(y)[idx] = o;
}

// ---------------------------------------------------------------------------
// BN + residual + ReLU, in-place fp32 (final output)
// ---------------------------------------------------------------------------
__global__ __launch_bounds__(256)
void bn_res_relu_kernel(float* __restrict__ x, const float* __restrict__ feats,
                        const float* __restrict__ sums, const float* __restrict__ gmm,
                        const float* __restrict__ bet, float invN, int total4)
{
    const int idx = blockIdx.x * blockDim.x + threadIdx.x;
    if (idx >= total4) return;
    float4 v = reinterpret_cast<float4*>(x)[idx];
    const float4 f = reinterpret_cast<const float4*>(feats)[idx];
    const int c0 = (idx & 15) * 4;
    float sc[4], sh[4];
#pragma unroll
    for (int i = 0; i < 4; ++i) {
        const int c = c0 + i;
        const float mu  = sums[c] * invN;
        const float var = sums[64 + c] * invN - mu * mu;
        const float rs  = rsqrtf(var + EPSV);
        sc[i] = gmm[c] * rs;
        sh[i] = bet[c] - mu * sc[i];
    }
    v.x = fmaxf(fmaf(v.x, sc[0], sh[0]) + f.x, 0.f);
    v.y = fmaxf(fmaf(v.y, sc[1], sh[1]) + f.y, 0.f);
    v.z = fmaxf(fmaf(v.z, sc[2], sh[2]) + f.z, 0.f);
    v.w = fmaxf(fmaf(v.w, sc[3], sh[3]) + f.w, 0.f);
    reinterpret_cast<float4*>(x)[idx] = v;
}

extern "C" void kernel_launch(void* const* d_in, const int* in_sizes, int n_in,
                              void* d_out, int out_size, void* d_ws, size_t ws_size,
                              hipStream_t stream)
{
    const float* feats = (const float*)d_in[0];
    const int*   nbr   = (const int*)d_in[1];
    const float* W1    = (const float*)d_in[2];
    const float* b1    = (const float*)d_in[3];
    const float* g1    = (const float*)d_in[4];
    const float* be1   = (const float*)d_in[5];
    const float* W2    = (const float*)d_in[6];
    const float* b2    = (const float*)d_in[7];
    const float* g2    = (const float*)d_in[8];
    const float* be2   = (const float*)d_in[9];
    float* out = (float*)d_out;

    const int N  = in_sizes[0] / NCH;          // 100000
    const int NC = N * NCH;                    // 6,400,000
    const float invN = 1.0f / (float)N;

    // workspace layout
    float*          h0   = (float*)d_ws;                       // [N*C] fp32
    unsigned short* fbf  = (unsigned short*)(h0 + NC);         // [N*C] bf16
    unsigned short* hbf  = fbf + NC;                           // [N*C] bf16
    unsigned short* wt1  = hbf + NC;                           // 110592 bf16
    unsigned short* wt2  = wt1 + KOFF * 4096;                  // 110592 bf16
    float*          stat = (float*)(wt2 + KOFF * 4096);        // 256 fp32

    const int total8   = NC / 8;                               // 800000
    const int castGrid = (total8 + 255) / 256;                 // 3125
    const int prepGrid = 1 + 108 + castGrid;                   // 3234
    const int convGrid = (N + 63) / 64;                        // 1563

    prep_kernel<<<prepGrid, 256, 0, stream>>>(feats, W1, W2, fbf, wt1, wt2,
                                              stat, total8);
    conv_mfma_kernel<<<convGrid, 256, 0, stream>>>(fbf, nbr, wt1, b1, h0, stat, N);
    bn_relu_bf16_kernel<<<castGrid, 256, 0, stream>>>(h0, stat, g1, be1, invN,
                                                      hbf, total8);
    conv_mfma_kernel<<<convGrid, 256, 0, stream>>>(hbf, nbr, wt2, b2, out,
                                                   stat + 128, N);
    bn_res_relu_kernel<<<(NC / 4 + 255) / 256, 256, 0, stream>>>(
        out, feats, stat + 128, g2, be2, invN, NC / 4);
}

// Round 5
// 296.607 us; speedup vs baseline: 1.0883x; 1.0833x over previous
//
#include <hip/hip_runtime.h>

#define NCH 64      // channels
#define KOFF 27     // kernel offsets
#define EPSV 1e-5f

typedef __attribute__((ext_vector_type(8))) short  bf16x8;
typedef __attribute__((ext_vector_type(4))) float  f32x4;
typedef __attribute__((ext_vector_type(8))) unsigned short u16x8;

__device__ __forceinline__ unsigned short f2bf(float x) {
    unsigned int u = __float_as_uint(x);
    u += 0x7fffu + ((u >> 16) & 1u);       // round-to-nearest-even
    return (unsigned short)(u >> 16);
}

// ---------------------------------------------------------------------------
// Fused prep: zero stats | W1->Wt1 | W2->Wt2 (B-fragment order) | feats->bf16
// Wt[(((k*2+s)*4+ct)*64+lane)*8 + j] = W[k][s*32+(lane>>4)*8+j][ct*16+(lane&15)]
// ---------------------------------------------------------------------------
__global__ __launch_bounds__(256)
void prep_kernel(const float* __restrict__ feats,
                 const float* __restrict__ W1, const float* __restrict__ W2,
                 unsigned short* __restrict__ fbf,
                 unsigned short* __restrict__ wt1, unsigned short* __restrict__ wt2,
                 float* __restrict__ stat, int total8)
{
    const int b = blockIdx.x;
    if (b == 0) {
        stat[threadIdx.x] = 0.f;           // 256 floats: stats1+stats2
        return;
    }
    if (b <= 108) {
        const float* W = (b <= 54) ? W1 : W2;
        unsigned short* Wt = (b <= 54) ? wt1 : wt2;
        const int t = (b <= 54 ? b - 1 : b - 55) * 256 + threadIdx.x; // 0..13823
        const int l  = t & 63;
        const int ct = (t >> 6) & 3;
        const int s  = (t >> 8) & 1;
        const int k  = t >> 9;
        const int d     = ct * 16 + (l & 15);
        const int cbase = s * 32 + (l >> 4) * 8;
        u16x8 o;
#pragma unroll
        for (int j = 0; j < 8; ++j)
            o[j] = f2bf(W[(size_t)k * 4096 + (size_t)(cbase + j) * 64 + d]);
        reinterpret_cast<u16x8*>(Wt)[t] = o;
        return;
    }
    const int idx = (b - 109) * 256 + threadIdx.x;
    if (idx >= total8) return;
    const float4* xp = reinterpret_cast<const float4*>(feats) + (size_t)idx * 2;
    const float4 a = xp[0], c = xp[1];
    u16x8 o;
    o[0] = f2bf(a.x); o[1] = f2bf(a.y); o[2] = f2bf(a.z); o[3] = f2bf(a.w);
    o[4] = f2bf(c.x); o[5] = f2bf(c.y); o[6] = f2bf(c.z); o[7] = f2bf(c.w);
    reinterpret_cast<u16x8*>(fbf)[idx] = o;
}

// ---------------------------------------------------------------------------
// Gathered conv via MFMA 16x16x32 bf16, one WAVE per block, 32 voxels x 64 ch.
// Barrier-free: wave-private LDS holds pre-scaled byte offsets; A and B
// fragments come straight from global with a register double-buffer (small
// enough to actually materialize: ~150 VGPRs). Per-block partial channel
// sums go to pstat[block*128 + {ch, 64+ch}] -- NO atomics in this kernel.
// ---------------------------------------------------------------------------
__global__ __launch_bounds__(64, 3)
void conv_mfma_kernel(const unsigned short* __restrict__ fin,
                      const int* __restrict__ nbr,
                      const unsigned short* __restrict__ Wt,
                      const float* __restrict__ bias,
                      float* __restrict__ out, float* __restrict__ pstat, int N)
{
    __shared__ int s_idx[32 * KOFF];          // byte offsets into fin

    const int lane = threadIdx.x;             // 0..63
    const int n0   = blockIdx.x * 32;
    const int m    = lane & 15;
    const int quad = lane >> 4;

    {   // stage 864 ints (32 voxels x 27 offsets), pre-scaled to byte offsets
        const int rem  = N - n0;
        const int maxi = (rem < 32 ? rem : 32) * KOFF;
        const int* nb  = nbr + (size_t)n0 * KOFF;
        for (int p = lane; p < 32 * KOFF; p += 64)
            s_idx[p] = ((p < maxi) ? nb[p] : 0) * (NCH * 2);
        // single wave: no barrier needed
    }

    f32x4 acc[2][4];
#pragma unroll
    for (int mt = 0; mt < 2; ++mt)
#pragma unroll
        for (int ct = 0; ct < 4; ++ct) acc[mt][ct] = (f32x4){0.f, 0.f, 0.f, 0.f};

    bf16x8 A[2][2][2];   // [buf][m-tile][s]
    bf16x8 B[2][2][4];   // [buf][s][ct]
    const char* finB = (const char*)fin;

#define LOADK(kk, p)                                                         \
    {                                                                        \
        _Pragma("unroll")                                                    \
        for (int mt = 0; mt < 2; ++mt) {                                     \
            const int ofs = s_idx[(mt * 16 + m) * KOFF + (kk)];              \
            const char* fp = finB + ofs + quad * 16;                         \
            A[p][mt][0] = *reinterpret_cast<const bf16x8*>(fp);              \
            A[p][mt][1] = *reinterpret_cast<const bf16x8*>(fp + 64);         \
        }                                                                    \
        const unsigned short* wp = Wt + (size_t)(kk) * 4096 + lane * 8;      \
        _Pragma("unroll")                                                    \
        for (int s = 0; s < 2; ++s)                                          \
            _Pragma("unroll")                                                \
            for (int ct = 0; ct < 4; ++ct)                                   \
                B[p][s][ct] =                                                \
                    *reinterpret_cast<const bf16x8*>(wp + (s * 4 + ct) * 512);\
    }

#define DOMFMA(p)                                                            \
    {                                                                        \
        _Pragma("unroll")                                                    \
        for (int mt = 0; mt < 2; ++mt)                                       \
            _Pragma("unroll")                                                \
            for (int s = 0; s < 2; ++s)                                      \
                _Pragma("unroll")                                            \
                for (int ct = 0; ct < 4; ++ct)                               \
                    acc[mt][ct] = __builtin_amdgcn_mfma_f32_16x16x32_bf16(   \
                        A[p][mt][s], B[p][s][ct], acc[mt][ct], 0, 0, 0);     \
    }

    LOADK(0, 0);
#pragma unroll 1
    for (int k = 0; k + 2 < KOFF; k += 2) {
        LOADK(k + 1, 1);
        DOMFMA(0);
        LOADK(k + 2, 0);
        DOMFMA(1);
    }
    // k=25 loaded in buf1 by last iter, k=26 in buf0
    DOMFMA(0);

    // epilogue: D layout col=lane&15, row=quad*4+reg; per-block partial stats
#pragma unroll
    for (int ct = 0; ct < 4; ++ct) {
        const int ch = ct * 16 + m;
        const float bv = bias[ch];
        float s = 0.f, q = 0.f;
#pragma unroll
        for (int mt = 0; mt < 2; ++mt) {
#pragma unroll
            for (int r = 0; r < 4; ++r) {
                const int vox = n0 + mt * 16 + quad * 4 + r;
                if (vox < N) {
                    const float v = acc[mt][ct][r] + bv;
                    out[(size_t)vox * NCH + ch] = v;
                    s += v;
                    q += v * v;
                }
            }
        }
        s += __shfl_xor(s, 16, 64);
        s += __shfl_xor(s, 32, 64);
        q += __shfl_xor(q, 16, 64);
        q += __shfl_xor(q, 32, 64);
        if (quad == 0) {
            float* pr = pstat + (size_t)blockIdx.x * 128;
            pr[ch]      = s;
            pr[64 + ch] = q;
        }
    }
#undef LOADK
#undef DOMFMA
}

// ---------------------------------------------------------------------------
// Fold per-block partial stats into stat[0:128]: 32 blocks, ~98 rows each,
// coalesced reads, one atomicAdd per channel per block (4k lane-atomics total)
// ---------------------------------------------------------------------------
__global__ __launch_bounds__(256)
void reduce_stats_kernel(const float* __restrict__ pstat, float* __restrict__ stat,
                         int rows)
{
    __shared__ float s_[256];
    const int ch = threadIdx.x & 127;
    const int h  = threadIdx.x >> 7;          // 0 or 1
    float acc = 0.f;
    for (int r = blockIdx.x * 2 + h; r < rows; r += gridDim.x * 2)
        acc += pstat[(size_t)r * 128 + ch];
    s_[threadIdx.x] = acc;
    __syncthreads();
    if (threadIdx.x < 128)
        atomicAdd(&stat[threadIdx.x], s_[threadIdx.x] + s_[threadIdx.x + 128]);
}

// ---------------------------------------------------------------------------
// BN + ReLU, fp32 in -> bf16 out (conv2's gather input). 8 elems/thread.
// ---------------------------------------------------------------------------
__global__ __launch_bounds__(256)
void bn_relu_bf16_kernel(const float* __restrict__ x, const float* __restrict__ sums,
                         const float* __restrict__ gmm, const float* __restrict__ bet,
                         float invN, unsigned short* __restrict__ y, int total8)
{
    const int idx = blockIdx.x * 256 + threadIdx.x;
    if (idx >= total8) return;
    const int c0 = (idx & 7) * 8;
    const float4* xp = reinterpret_cast<const float4*>(x) + (size_t)idx * 2;
    const float4 a = xp[0], b = xp[1];
    float v[8] = {a.x, a.y, a.z, a.w, b.x, b.y, b.z, b.w};
    u16x8 o;
#pragma unroll
    for (int i = 0; i < 8; ++i) {
        const int c = c0 + i;
        const float mu  = sums[c] * invN;
        const float var = sums[64 + c] * invN - mu * mu;
        const float rs  = rsqrtf(var + EPSV);
        const float sc  = gmm[c] * rs;
        const float sh  = bet[c] - mu * sc;
        o[i] = f2bf(fmaxf(fmaf(v[i], sc, sh), 0.f));
    }
    reinterpret_cast<u16x8*>(y)[idx] = o;
}

// ---------------------------------------------------------------------------
// BN + residual + ReLU, in-place fp32 (final output)
// ---------------------------------------------------------------------------
__global__ __launch_bounds__(256)
void bn_res_relu_kernel(float* __restrict__ x, const float* __restrict__ feats,
                        const float* __restrict__ sums, const float* __restrict__ gmm,
                        const float* __restrict__ bet, float invN, int total4)
{
    const int idx = blockIdx.x * blockDim.x + threadIdx.x;
    if (idx >= total4) return;
    float4 v = reinterpret_cast<float4*>(x)[idx];
    const float4 f = reinterpret_cast<const float4*>(feats)[idx];
    const int c0 = (idx & 15) * 4;
    float sc[4], sh[4];
#pragma unroll
    for (int i = 0; i < 4; ++i) {
        const int c = c0 + i;
        const float mu  = sums[c] * invN;
        const float var = sums[64 + c] * invN - mu * mu;
        const float rs  = rsqrtf(var + EPSV);
        sc[i] = gmm[c] * rs;
        sh[i] = bet[c] - mu * sc[i];
    }
    v.x = fmaxf(fmaf(v.x, sc[0], sh[0]) + f.x, 0.f);
    v.y = fmaxf(fmaf(v.y, sc[1], sh[1]) + f.y, 0.f);
    v.z = fmaxf(fmaf(v.z, sc[2], sh[2]) + f.z, 0.f);
    v.w = fmaxf(fmaf(v.w, sc[3], sh[3]) + f.w, 0.f);
    reinterpret_cast<float4*>(x)[idx] = v;
}

extern "C" void kernel_launch(void* const* d_in, const int* in_sizes, int n_in,
                              void* d_out, int out_size, void* d_ws, size_t ws_size,
                              hipStream_t stream)
{
    const float* feats = (const float*)d_in[0];
    const int*   nbr   = (const int*)d_in[1];
    const float* W1    = (const float*)d_in[2];
    const float* b1    = (const float*)d_in[3];
    const float* g1    = (const float*)d_in[4];
    const float* be1   = (const float*)d_in[5];
    const float* W2    = (const float*)d_in[6];
    const float* b2    = (const float*)d_in[7];
    const float* g2    = (const float*)d_in[8];
    const float* be2   = (const float*)d_in[9];
    float* out = (float*)d_out;

    const int N  = in_sizes[0] / NCH;          // 100000
    const int NC = N * NCH;                    // 6,400,000
    const float invN = 1.0f / (float)N;

    // workspace layout
    float*          h0   = (float*)d_ws;                       // [N*C] fp32
    unsigned short* fbf  = (unsigned short*)(h0 + NC);         // [N*C] bf16
    unsigned short* hbf  = fbf + NC;                           // [N*C] bf16
    unsigned short* wt1  = hbf + NC;                           // 110592 bf16
    unsigned short* wt2  = wt1 + KOFF * 4096;                  // 110592 bf16
    float*          stat = (float*)(wt2 + KOFF * 4096);        // 256 fp32

    const int total8   = NC / 8;                               // 800000
    const int castGrid = (total8 + 255) / 256;                 // 3125
    const int prepGrid = 1 + 108 + castGrid;                   // 3234
    const int convGrid = (N + 31) / 32;                        // 3125

    // pstat scratch aliases dead regions: conv1's partials go in d_out
    // (overwritten later by conv2), conv2's partials go in h0 (dead after bn).
    float* pstat1 = out;
    float* pstat2 = h0;

    prep_kernel<<<prepGrid, 256, 0, stream>>>(feats, W1, W2, fbf, wt1, wt2,
                                              stat, total8);
    conv_mfma_kernel<<<convGrid, 64, 0, stream>>>(fbf, nbr, wt1, b1, h0,
                                                  pstat1, N);
    reduce_stats_kernel<<<32, 256, 0, stream>>>(pstat1, stat, convGrid);
    bn_relu_bf16_kernel<<<castGrid, 256, 0, stream>>>(h0, stat, g1, be1, invN,
                                                      hbf, total8);
    conv_mfma_kernel<<<convGrid, 64, 0, stream>>>(hbf, nbr, wt2, b2, out,
                                                  pstat2, N);
    reduce_stats_kernel<<<32, 256, 0, stream>>>(pstat2, stat + 128, convGrid);
    bn_res_relu_kernel<<<(NC / 4 + 255) / 256, 256, 0, stream>>>(
        out, feats, stat + 128, g2, be2, invN, NC / 4);
}